// Round 1
// baseline (4924.128 us; speedup 1.0000x reference)
//
#include <hip/hip_runtime.h>
#include <math.h>

// Problem constants
#define B_   8
#define C_   256
#define P_   64
#define H_   64
#define W_   64
#define HW_  4096   // H_*W_

// Workspace layout (floats):
//  top  [b][p][m]   : B*P*HW  = 2097152
//  cen  [b][p][n]   : B*P*HW  = 2097152
//  bot  [b][m][c]   : B*HW*C  = 8388608   (transposed conv output)
//  y    [b][c][h][w]: B*C*HW  = 8388608
//  pmax [b][256], psum [b][256], MZ[b*2]
// total ~= 84 MB

#define OFF_TOP  ((size_t)0)
#define OFF_CEN  ((size_t)2097152)
#define OFF_BOT  ((size_t)4194304)
#define OFF_Y    ((size_t)12582912)
#define OFF_PMAX ((size_t)20971520)
#define OFF_PSUM ((size_t)20973568)
#define OFF_MZ   ((size_t)20975616)

// ---------------------------------------------------------------------------
// 1x1 conv:  out[b][p][m] = sum_c w[p][c]*x[b][c][m] + bias[p]
// grid: (HW/256, P/4, B), block 256, 4 p per thread
__global__ __launch_bounds__(256) void pab_conv1x1(
    const float* __restrict__ x, const float* __restrict__ w,
    const float* __restrict__ bias, float* __restrict__ out) {
  const int m  = blockIdx.x * 256 + threadIdx.x;
  const int p0 = blockIdx.y * 4;
  const int b  = blockIdx.z;
  const float* xb = x + (size_t)b * C_ * HW_ + m;
  const float* w0 = w + (size_t)(p0 + 0) * C_;
  const float* w1 = w + (size_t)(p0 + 1) * C_;
  const float* w2 = w + (size_t)(p0 + 2) * C_;
  const float* w3 = w + (size_t)(p0 + 3) * C_;
  float a0 = bias[p0 + 0], a1 = bias[p0 + 1], a2 = bias[p0 + 2], a3 = bias[p0 + 3];
#pragma unroll 4
  for (int c = 0; c < C_; ++c) {
    float xv = xb[(size_t)c * HW_];
    a0 = fmaf(w0[c], xv, a0);
    a1 = fmaf(w1[c], xv, a1);
    a2 = fmaf(w2[c], xv, a2);
    a3 = fmaf(w3[c], xv, a3);
  }
  size_t ob = ((size_t)b * P_ + p0) * HW_ + m;
  out[ob]          = a0;
  out[ob + HW_]    = a1;
  out[ob + 2*HW_]  = a2;
  out[ob + 3*HW_]  = a3;
}

// ---------------------------------------------------------------------------
// 3x3 conv, pad=1 (cross-correlation, OIHW weights).
// transpose_out==0: out[b][co][n];  ==1: out[b][n][co] (for bottom -> [m][c])
// grid: (HW/256, C/4, B), block 256, 4 co per thread
__global__ __launch_bounds__(256) void pab_conv3x3(
    const float* __restrict__ x, const float* __restrict__ wgt,
    const float* __restrict__ bias, float* __restrict__ out,
    const int transpose_out) {
  const int n   = blockIdx.x * 256 + threadIdx.x;
  const int co0 = blockIdx.y * 4;
  const int b   = blockIdx.z;
  const int h = n >> 6, wc = n & 63;
  const float* xb = x + (size_t)b * C_ * HW_;
  float acc[4] = {bias[co0], bias[co0 + 1], bias[co0 + 2], bias[co0 + 3]};
  for (int ci = 0; ci < C_; ++ci) {
    const float* xc = xb + (size_t)ci * HW_;
    const float* wk = wgt + ((size_t)co0 * C_ + ci) * 9;
#pragma unroll
    for (int k = 0; k < 9; ++k) {
      const int dh = k / 3 - 1, dw = k % 3 - 1;
      const int hh = h + dh, ww = wc + dw;
      const float xv = ((unsigned)hh < (unsigned)H_ && (unsigned)ww < (unsigned)W_)
                           ? xc[hh * W_ + ww] : 0.f;
#pragma unroll
      for (int t = 0; t < 4; ++t)
        acc[t] = fmaf(wk[(size_t)t * C_ * 9 + k], xv, acc[t]);
    }
  }
  if (transpose_out) {
    size_t base = ((size_t)b * HW_ + n) * C_ + co0;
    out[base]     = acc[0];
    out[base + 1] = acc[1];
    out[base + 2] = acc[2];
    out[base + 3] = acc[3];
  } else {
    size_t base = ((size_t)b * C_ + co0) * HW_ + n;
    out[base]          = acc[0];
    out[base + HW_]    = acc[1];
    out[base + 2*HW_]  = acc[2];
    out[base + 3*HW_]  = acc[3];
  }
}

// ---------------------------------------------------------------------------
// Pass 1: per-block local (max, rescaled expsum) over a 16-row tile of the
// (HW x HW) score matrix. s[n][m] = sum_p cen[b][p][n]*top[b][p][m].
#define TN1 16
__global__ __launch_bounds__(256) void pab_pass1(
    const float* __restrict__ cen, const float* __restrict__ top,
    float* __restrict__ pmax, float* __restrict__ psum) {
  __shared__ float cen_s[P_][TN1];   // [p][t]
  __shared__ float red_m[256];
  __shared__ float red_s[256];
  const int b  = blockIdx.y;
  const int n0 = blockIdx.x * TN1;
  const int tid = threadIdx.x;
  for (int i = tid; i < TN1 * P_; i += 256) {
    const int p = i / TN1, t = i % TN1;
    cen_s[p][t] = cen[((size_t)b * P_ + p) * HW_ + n0 + t];
  }
  __syncthreads();
  const float* topb = top + (size_t)b * P_ * HW_;
  float mx = -3.0e38f, sm = 0.f;
  for (int j = 0; j < HW_ / 256; ++j) {
    const int m = j * 256 + tid;
    float part[TN1];
#pragma unroll
    for (int t = 0; t < TN1; ++t) part[t] = 0.f;
    for (int p = 0; p < P_; ++p) {
      const float tv = topb[(size_t)p * HW_ + m];
#pragma unroll
      for (int t = 0; t < TN1; ++t) part[t] = fmaf(cen_s[p][t], tv, part[t]);
    }
#pragma unroll
    for (int t = 0; t < TN1; ++t) {
      const float s = part[t];
      if (s > mx) { sm = sm * __expf(mx - s) + 1.f; mx = s; }
      else        { sm += __expf(s - mx); }
    }
  }
  red_m[tid] = mx; red_s[tid] = sm;
  __syncthreads();
  for (int off = 128; off > 0; off >>= 1) {
    if (tid < off) {
      const float m1 = red_m[tid], s1 = red_s[tid];
      const float m2 = red_m[tid + off], s2 = red_s[tid + off];
      const float M = fmaxf(m1, m2);
      red_m[tid] = M;
      red_s[tid] = s1 * __expf(m1 - M) + s2 * __expf(m2 - M);
    }
    __syncthreads();
  }
  if (tid == 0) {
    pmax[(size_t)b * (HW_ / TN1) + blockIdx.x] = red_m[0];
    psum[(size_t)b * (HW_ / TN1) + blockIdx.x] = red_s[0];
  }
}

// Combine 256 partials per batch -> global (M, Z)
__global__ __launch_bounds__(256) void pab_reduce(
    const float* __restrict__ pmax, const float* __restrict__ psum,
    float* __restrict__ MZ) {
  __shared__ float red_m[256];
  __shared__ float red_s[256];
  const int b = blockIdx.x, tid = threadIdx.x;
  red_m[tid] = pmax[(size_t)b * 256 + tid];
  red_s[tid] = psum[(size_t)b * 256 + tid];
  __syncthreads();
  for (int off = 128; off > 0; off >>= 1) {
    if (tid < off) {
      const float m1 = red_m[tid], s1 = red_s[tid];
      const float m2 = red_m[tid + off], s2 = red_s[tid + off];
      const float M = fmaxf(m1, m2);
      red_m[tid] = M;
      red_s[tid] = s1 * __expf(m1 - M) + s2 * __expf(m2 - M);
    }
    __syncthreads();
  }
  if (tid == 0) { MZ[b * 2] = red_m[0]; MZ[b * 2 + 1] = red_s[0]; }
}

// ---------------------------------------------------------------------------
// Pass 2: attn[n][c] = (1/Z) * sum_m exp(s[n][m]-M) * bot[m][c]
// then y[b] flat(n*C+c) = x[b] flat + attn  (reshape, NOT transpose!)
#define TN2 16
#define MC  512
#define WPAD 20
__global__ __launch_bounds__(256) void pab_pass2(
    const float* __restrict__ cen, const float* __restrict__ top,
    const float* __restrict__ bot, const float* __restrict__ x,
    const float* __restrict__ MZ, float* __restrict__ y) {
  __shared__ float cen_s[P_][TN2];      // [p][t]
  __shared__ float w_lds[MC][WPAD];     // [m_local][t], padded
  const int b  = blockIdx.y;
  const int n0 = blockIdx.x * TN2;
  const int tid = threadIdx.x;
  const float Mg  = MZ[b * 2];
  const float invZ = 1.f / MZ[b * 2 + 1];
  for (int i = tid; i < TN2 * P_; i += 256) {
    const int p = i / TN2, t = i % TN2;
    cen_s[p][t] = cen[((size_t)b * P_ + p) * HW_ + n0 + t];
  }
  const float* topb = top + (size_t)b * P_ * HW_;
  const float* botb = bot + (size_t)b * HW_ * C_;
  float acc[TN2];
#pragma unroll
  for (int t = 0; t < TN2; ++t) acc[t] = 0.f;
  __syncthreads();
  for (int ch = 0; ch < HW_ / MC; ++ch) {
    // phase A: scores -> weights in LDS
#pragma unroll
    for (int jj = 0; jj < MC / 256; ++jj) {
      const int ml = jj * 256 + tid;
      const int m  = ch * MC + ml;
      float part[TN2];
#pragma unroll
      for (int t = 0; t < TN2; ++t) part[t] = 0.f;
      for (int p = 0; p < P_; ++p) {
        const float tv = topb[(size_t)p * HW_ + m];
#pragma unroll
        for (int t = 0; t < TN2; ++t) part[t] = fmaf(cen_s[p][t], tv, part[t]);
      }
#pragma unroll
      for (int t = 0; t < TN2; ++t) w_lds[ml][t] = __expf(part[t] - Mg);
    }
    __syncthreads();
    // phase B: accumulate over m-chunk; thread owns column c = tid
    for (int ml = 0; ml < MC; ++ml) {
      const float bv = botb[(size_t)(ch * MC + ml) * C_ + tid];
#pragma unroll
      for (int t = 0; t < TN2; ++t) acc[t] = fmaf(w_lds[ml][t], bv, acc[t]);
    }
    __syncthreads();
  }
  const size_t xb = (size_t)b * (C_ * HW_);
#pragma unroll
  for (int t = 0; t < TN2; ++t) {
    const size_t flat = (size_t)(n0 + t) * C_ + tid;  // reshape semantics
    y[xb + flat] = x[xb + flat] + acc[t] * invZ;
  }
}

// ---------------------------------------------------------------------------
extern "C" void kernel_launch(void* const* d_in, const int* in_sizes, int n_in,
                              void* d_out, int out_size, void* d_ws, size_t ws_size,
                              hipStream_t stream) {
  const float* x        = (const float*)d_in[0];
  const float* top_w    = (const float*)d_in[1];
  const float* top_b    = (const float*)d_in[2];
  const float* center_w = (const float*)d_in[3];
  const float* center_b = (const float*)d_in[4];
  const float* bottom_w = (const float*)d_in[5];
  const float* bottom_b = (const float*)d_in[6];
  const float* out_w    = (const float*)d_in[7];
  const float* out_b    = (const float*)d_in[8];
  float* ws = (float*)d_ws;
  float* w_top  = ws + OFF_TOP;
  float* w_cen  = ws + OFF_CEN;
  float* w_bot  = ws + OFF_BOT;
  float* w_y    = ws + OFF_Y;
  float* w_pmax = ws + OFF_PMAX;
  float* w_psum = ws + OFF_PSUM;
  float* w_MZ   = ws + OFF_MZ;
  (void)in_sizes; (void)n_in; (void)out_size; (void)ws_size;

  // 1x1 convs -> top, center
  pab_conv1x1<<<dim3(HW_ / 256, P_ / 4, B_), 256, 0, stream>>>(x, top_w, top_b, w_top);
  pab_conv1x1<<<dim3(HW_ / 256, P_ / 4, B_), 256, 0, stream>>>(x, center_w, center_b, w_cen);
  // 3x3 conv -> bottom, stored transposed as [m][c]
  pab_conv3x3<<<dim3(HW_ / 256, C_ / 4, B_), 256, 0, stream>>>(x, bottom_w, bottom_b, w_bot, 1);
  // global-softmax stats (two-level)
  pab_pass1<<<dim3(HW_ / TN1, B_), 256, 0, stream>>>(w_cen, w_top, w_pmax, w_psum);
  pab_reduce<<<dim3(B_), 256, 0, stream>>>(w_pmax, w_psum, w_MZ);
  // attention apply + residual (flat reshape add) -> y
  pab_pass2<<<dim3(HW_ / TN2, B_), 256, 0, stream>>>(w_cen, w_top, w_bot, x, w_MZ, w_y);
  // final 3x3 conv -> d_out
  pab_conv3x3<<<dim3(HW_ / 256, C_ / 4, B_), 256, 0, stream>>>(w_y, out_w, out_b, (float*)d_out, 0);
}

// Round 3
// 2089.798 us; speedup vs baseline: 2.3563x; 2.3563x over previous
//
#include <hip/hip_runtime.h>
#include <hip/hip_bf16.h>
#include <math.h>

// Problem constants
#define B_   8
#define C_   256
#define P_   64
#define H_   64
#define W_   64
#define HW_  4096   // H_*W_

// Workspace layout (float units):
#define OFF_TOP  ((size_t)0)          // [b][p][m] fp32 : 2097152
#define OFF_CEN  ((size_t)2097152)    // [b][p][n] fp32 : 2097152
#define OFF_BOT  ((size_t)4194304)    // [b][m][c] fp32 : 8388608
#define OFF_Y    ((size_t)12582912)   // [b][c*hw] fp32 : 8388608
#define OFF_PMAX ((size_t)20971520)
#define OFF_PSUM ((size_t)20973568)
#define OFF_MZ   ((size_t)20975616)
#define OFF_XT   ((size_t)20975744)   // bf16 [b][n][c] : 8388608 bf16 = 4194304 f
#define OFF_YT   ((size_t)25170048)   // bf16 [b][n][c] : 4194304 f
#define OFF_WK1  ((size_t)29364352)   // bf16 [9][co][ci]: 294912 f
#define OFF_WK2  ((size_t)29659264)   // bf16 [9][co][ci]: 294912 f

typedef __attribute__((ext_vector_type(8))) short bf16x8;
typedef __attribute__((ext_vector_type(4))) float f32x4;

// ---------------------------------------------------------------------------
// fp32 [b][C][HW] -> bf16 [b][HW][C]  (tiled transpose + convert)
__global__ __launch_bounds__(256) void pab_tcvt(
    const float* __restrict__ in, __hip_bfloat16* __restrict__ out) {
  __shared__ float t[64][65];
  const int b = blockIdx.z, c0 = blockIdx.y * 64, n0 = blockIdx.x * 64;
  const int tid = threadIdx.x;
  const float* ib = in + ((size_t)b * C_ + c0) * HW_ + n0;
  for (int i = tid; i < 4096; i += 256) {
    const int c = i >> 6, n = i & 63;
    t[c][n] = ib[(size_t)c * HW_ + n];
  }
  __syncthreads();
  __hip_bfloat16* ob = out + ((size_t)b * HW_ + n0) * C_ + c0;
  for (int i = tid; i < 4096; i += 256) {
    const int n = i >> 6, c = i & 63;
    ob[(size_t)n * C_ + c] = __float2bfloat16(t[c][n]);
  }
}

// 3x3 weights: fp32 [co][ci][9] -> bf16 [tap][co][ci]
__global__ __launch_bounds__(256) void pab_repack_w3(
    const float* __restrict__ w, __hip_bfloat16* __restrict__ out) {
  const int idx = blockIdx.x * 256 + threadIdx.x;  // < 589824
  const int co  = idx / 2304;
  const int rem = idx - co * 2304;
  const int ci  = rem / 9;
  const int k   = rem - ci * 9;
  out[((size_t)k * C_ + co) * C_ + ci] = __float2bfloat16(w[idx]);
}

// ---------------------------------------------------------------------------
// fp32 1x1 conv (precision-critical: feeds the global softmax score chain)
// out[b][p][m] = sum_c w[p][c]*x[b][c][m] + bias[p]
__global__ __launch_bounds__(256) void pab_conv1x1(
    const float* __restrict__ x, const float* __restrict__ w,
    const float* __restrict__ bias, float* __restrict__ out) {
  const int m  = blockIdx.x * 256 + threadIdx.x;
  const int p0 = blockIdx.y * 4;
  const int b  = blockIdx.z;
  const float* xb = x + (size_t)b * C_ * HW_ + m;
  const float* w0 = w + (size_t)(p0 + 0) * C_;
  const float* w1 = w + (size_t)(p0 + 1) * C_;
  const float* w2 = w + (size_t)(p0 + 2) * C_;
  const float* w3 = w + (size_t)(p0 + 3) * C_;
  float a0 = bias[p0 + 0], a1 = bias[p0 + 1], a2 = bias[p0 + 2], a3 = bias[p0 + 3];
#pragma unroll 4
  for (int c = 0; c < C_; ++c) {
    float xv = xb[(size_t)c * HW_];
    a0 = fmaf(w0[c], xv, a0);
    a1 = fmaf(w1[c], xv, a1);
    a2 = fmaf(w2[c], xv, a2);
    a3 = fmaf(w3[c], xv, a3);
  }
  size_t ob = ((size_t)b * P_ + p0) * HW_ + m;
  out[ob]          = a0;
  out[ob + HW_]    = a1;
  out[ob + 2*HW_]  = a2;
  out[ob + 3*HW_]  = a3;
}

// ---------------------------------------------------------------------------
// 3x3 conv as implicit GEMM with MFMA (bf16 in, fp32 accum).
// Block: 256 thr = 4 waves; block tile 256co x 64n (one image row); wave = 64co x 64n.
// transpose_out==0: out [b][co][n]; ==1: out [b][n][co].
__global__ __launch_bounds__(256) void pab_conv3x3_mfma(
    const __hip_bfloat16* __restrict__ xT, const __hip_bfloat16* __restrict__ wk,
    const float* __restrict__ bias, float* __restrict__ out,
    const int transpose_out) {
  __shared__ float lds[4][64][65];
  const int b   = blockIdx.y;
  const int n0  = blockIdx.x * 64;  // one image row
  const int h0  = n0 >> 6;
  const int tid = threadIdx.x;
  const int lane = tid & 63;
  const int wv   = tid >> 6;
  const int nl   = lane & 15;   // n (B) / co (A) index within fragment
  const int kg   = lane >> 4;   // k-group
  const int cobase = wv * 64;

  const short* xTb = (const short*)xT + (size_t)b * HW_ * C_;
  const short* wks = (const short*)wk;

  f32x4 acc[4][4];
#pragma unroll
  for (int i = 0; i < 4; ++i)
#pragma unroll
    for (int j = 0; j < 4; ++j) acc[i][j] = (f32x4)0.f;

  for (int tap = 0; tap < 9; ++tap) {
    const int dh = tap / 3 - 1, dw = tap % 3 - 1;
    const bool vh = (unsigned)(h0 + dh) < 64u;
    const int doff = dh * 64 + dw;
    bool val[4];
    const short* bp[4];
#pragma unroll
    for (int j = 0; j < 4; ++j) {
      const int w = j * 16 + nl;
      val[j] = vh && ((unsigned)(w + dw) < 64u);
      bp[j]  = xTb + (size_t)(n0 + w + doff) * C_ + kg * 8;
    }
    const short* ap = wks + (size_t)tap * C_ * C_ + (size_t)(cobase + nl) * C_ + kg * 8;
#pragma unroll 2
    for (int ci0 = 0; ci0 < C_; ci0 += 32) {
      bf16x8 a[4], bb[4];
#pragma unroll
      for (int i = 0; i < 4; ++i) a[i] = *(const bf16x8*)(ap + (size_t)i * 16 * C_ + ci0);
#pragma unroll
      for (int j = 0; j < 4; ++j)
        bb[j] = val[j] ? *(const bf16x8*)(bp[j] + ci0) : (bf16x8)(short)0;
#pragma unroll
      for (int i = 0; i < 4; ++i)
#pragma unroll
        for (int j = 0; j < 4; ++j)
          acc[i][j] = __builtin_amdgcn_mfma_f32_16x16x32_bf16(a[i], bb[j], acc[i][j], 0, 0, 0);
    }
  }
  // stage wave tile to LDS: lds[wv][co_local][n_local]
#pragma unroll
  for (int i = 0; i < 4; ++i) {
    const int co_l = i * 16 + kg * 4;
#pragma unroll
    for (int j = 0; j < 4; ++j)
#pragma unroll
      for (int r = 0; r < 4; ++r)
        lds[wv][co_l + r][j * 16 + nl] = acc[i][j][r];
  }
  __syncthreads();
  if (!transpose_out) {
#pragma unroll 4
    for (int row = 0; row < 64; ++row) {
      const int co = cobase + row;
      out[((size_t)b * C_ + co) * HW_ + n0 + lane] = lds[wv][row][lane] + bias[co];
    }
  } else {
    const int co = cobase + lane;
    const float bs = bias[co];
#pragma unroll 4
    for (int row = 0; row < 64; ++row)
      out[((size_t)b * HW_ + n0 + row) * C_ + co] = lds[wv][lane][row] + bs;
  }
}

// ---------------------------------------------------------------------------
// Pass 1: per-block local (max, rescaled expsum) over a 16-row tile of scores.
#define TN1 16
__global__ __launch_bounds__(256) void pab_pass1(
    const float* __restrict__ cen, const float* __restrict__ top,
    float* __restrict__ pmax, float* __restrict__ psum) {
  __shared__ float cen_s[P_][TN1];
  __shared__ float red_m[256];
  __shared__ float red_s[256];
  const int b  = blockIdx.y;
  const int n0 = blockIdx.x * TN1;
  const int tid = threadIdx.x;
  for (int i = tid; i < TN1 * P_; i += 256) {
    const int p = i / TN1, t = i % TN1;
    cen_s[p][t] = cen[((size_t)b * P_ + p) * HW_ + n0 + t];
  }
  __syncthreads();
  const float* topb = top + (size_t)b * P_ * HW_;
  float mx = -3.0e38f, sm = 0.f;
  for (int j = 0; j < HW_ / 256; ++j) {
    const int m = j * 256 + tid;
    float part[TN1];
#pragma unroll
    for (int t = 0; t < TN1; ++t) part[t] = 0.f;
    for (int p = 0; p < P_; ++p) {
      const float tv = topb[(size_t)p * HW_ + m];
#pragma unroll
      for (int t = 0; t < TN1; ++t) part[t] = fmaf(cen_s[p][t], tv, part[t]);
    }
#pragma unroll
    for (int t = 0; t < TN1; ++t) {
      const float s = part[t];
      if (s > mx) { sm = sm * __expf(mx - s) + 1.f; mx = s; }
      else        { sm += __expf(s - mx); }
    }
  }
  red_m[tid] = mx; red_s[tid] = sm;
  __syncthreads();
  for (int off = 128; off > 0; off >>= 1) {
    if (tid < off) {
      const float m1 = red_m[tid], s1 = red_s[tid];
      const float m2 = red_m[tid + off], s2 = red_s[tid + off];
      const float M = fmaxf(m1, m2);
      red_m[tid] = M;
      red_s[tid] = s1 * __expf(m1 - M) + s2 * __expf(m2 - M);
    }
    __syncthreads();
  }
  if (tid == 0) {
    pmax[(size_t)b * (HW_ / TN1) + blockIdx.x] = red_m[0];
    psum[(size_t)b * (HW_ / TN1) + blockIdx.x] = red_s[0];
  }
}

__global__ __launch_bounds__(256) void pab_reduce(
    const float* __restrict__ pmax, const float* __restrict__ psum,
    float* __restrict__ MZ) {
  __shared__ float red_m[256];
  __shared__ float red_s[256];
  const int b = blockIdx.x, tid = threadIdx.x;
  red_m[tid] = pmax[(size_t)b * 256 + tid];
  red_s[tid] = psum[(size_t)b * 256 + tid];
  __syncthreads();
  for (int off = 128; off > 0; off >>= 1) {
    if (tid < off) {
      const float m1 = red_m[tid], s1 = red_s[tid];
      const float m2 = red_m[tid + off], s2 = red_s[tid + off];
      const float M = fmaxf(m1, m2);
      red_m[tid] = M;
      red_s[tid] = s1 * __expf(m1 - M) + s2 * __expf(m2 - M);
    }
    __syncthreads();
  }
  if (tid == 0) { MZ[b * 2] = red_m[0]; MZ[b * 2 + 1] = red_s[0]; }
}

// ---------------------------------------------------------------------------
// Pass 2: attn[n][c] = (1/Z) * sum_m exp(s[n][m]-M) * bot[m][c]
// then y flat(n*C+c) = x flat + attn (reshape semantics).
#define TN2 16
#define MC  512
#define WPAD 20
__global__ __launch_bounds__(256) void pab_pass2(
    const float* __restrict__ cen, const float* __restrict__ top,
    const float* __restrict__ bot, const float* __restrict__ x,
    const float* __restrict__ MZ, float* __restrict__ y) {
  __shared__ float cen_s[P_][TN2];
  __shared__ float w_lds[MC][WPAD];
  const int b  = blockIdx.y;
  const int n0 = blockIdx.x * TN2;
  const int tid = threadIdx.x;
  const float Mg   = MZ[b * 2];
  const float invZ = 1.f / MZ[b * 2 + 1];
  for (int i = tid; i < TN2 * P_; i += 256) {
    const int p = i / TN2, t = i % TN2;
    cen_s[p][t] = cen[((size_t)b * P_ + p) * HW_ + n0 + t];
  }
  const float* topb = top + (size_t)b * P_ * HW_;
  const float* botb = bot + (size_t)b * HW_ * C_;
  float acc[TN2];
#pragma unroll
  for (int t = 0; t < TN2; ++t) acc[t] = 0.f;
  __syncthreads();
  for (int ch = 0; ch < HW_ / MC; ++ch) {
#pragma unroll
    for (int jj = 0; jj < MC / 256; ++jj) {
      const int ml = jj * 256 + tid;
      const int m  = ch * MC + ml;
      float part[TN2];
#pragma unroll
      for (int t = 0; t < TN2; ++t) part[t] = 0.f;
      for (int p = 0; p < P_; ++p) {
        const float tv = topb[(size_t)p * HW_ + m];
#pragma unroll
        for (int t = 0; t < TN2; ++t) part[t] = fmaf(cen_s[p][t], tv, part[t]);
      }
#pragma unroll
      for (int t = 0; t < TN2; ++t) w_lds[ml][t] = __expf(part[t] - Mg);
    }
    __syncthreads();
    for (int ml = 0; ml < MC; ++ml) {
      const float bv = botb[(size_t)(ch * MC + ml) * C_ + tid];
#pragma unroll
      for (int t = 0; t < TN2; ++t) acc[t] = fmaf(w_lds[ml][t], bv, acc[t]);
    }
    __syncthreads();
  }
  const size_t xb = (size_t)b * (C_ * HW_);
#pragma unroll
  for (int t = 0; t < TN2; ++t) {
    const size_t flat = (size_t)(n0 + t) * C_ + tid;  // reshape semantics
    y[xb + flat] = x[xb + flat] + acc[t] * invZ;
  }
}

// ---------------------------------------------------------------------------
extern "C" void kernel_launch(void* const* d_in, const int* in_sizes, int n_in,
                              void* d_out, int out_size, void* d_ws, size_t ws_size,
                              hipStream_t stream) {
  const float* x        = (const float*)d_in[0];
  const float* top_w    = (const float*)d_in[1];
  const float* top_b    = (const float*)d_in[2];
  const float* center_w = (const float*)d_in[3];
  const float* center_b = (const float*)d_in[4];
  const float* bottom_w = (const float*)d_in[5];
  const float* bottom_b = (const float*)d_in[6];
  const float* out_w    = (const float*)d_in[7];
  const float* out_b    = (const float*)d_in[8];
  float* ws = (float*)d_ws;
  float* w_top  = ws + OFF_TOP;
  float* w_cen  = ws + OFF_CEN;
  float* w_bot  = ws + OFF_BOT;
  float* w_y    = ws + OFF_Y;
  float* w_pmax = ws + OFF_PMAX;
  float* w_psum = ws + OFF_PSUM;
  float* w_MZ   = ws + OFF_MZ;
  __hip_bfloat16* w_xt  = (__hip_bfloat16*)(ws + OFF_XT);
  __hip_bfloat16* w_yt  = (__hip_bfloat16*)(ws + OFF_YT);
  __hip_bfloat16* w_wk1 = (__hip_bfloat16*)(ws + OFF_WK1);
  __hip_bfloat16* w_wk2 = (__hip_bfloat16*)(ws + OFF_WK2);
  (void)in_sizes; (void)n_in; (void)out_size; (void)ws_size;

  // prologue: transpose/convert x + repack 3x3 weights to bf16
  pab_tcvt<<<dim3(HW_ / 64, C_ / 64, B_), 256, 0, stream>>>(x, w_xt);
  pab_repack_w3<<<dim3(2304), 256, 0, stream>>>(bottom_w, w_wk1);
  pab_repack_w3<<<dim3(2304), 256, 0, stream>>>(out_w, w_wk2);

  // 1x1 convs in fp32 (score-chain precision)
  pab_conv1x1<<<dim3(HW_ / 256, P_ / 4, B_), 256, 0, stream>>>(x, top_w, top_b, w_top);
  pab_conv1x1<<<dim3(HW_ / 256, P_ / 4, B_), 256, 0, stream>>>(x, center_w, center_b, w_cen);
  // 3x3 conv -> bottom [m][c] (MFMA, transposed epilogue)
  pab_conv3x3_mfma<<<dim3(HW_ / 64, B_), 256, 0, stream>>>(w_xt, w_wk1, bottom_b, w_bot, 1);

  // global-softmax stats + apply
  pab_pass1<<<dim3(HW_ / TN1, B_), 256, 0, stream>>>(w_cen, w_top, w_pmax, w_psum);
  pab_reduce<<<dim3(B_), 256, 0, stream>>>(w_pmax, w_psum, w_MZ);
  pab_pass2<<<dim3(HW_ / TN2, B_), 256, 0, stream>>>(w_cen, w_top, w_bot, x, w_MZ, w_y);

  // final 3x3 conv (MFMA) on y
  pab_tcvt<<<dim3(HW_ / 64, C_ / 64, B_), 256, 0, stream>>>(w_y, w_yt);
  pab_conv3x3_mfma<<<dim3(HW_ / 64, B_), 256, 0, stream>>>(w_yt, w_wk2, out_b, (float*)d_out, 0);
}

// Round 5
// 769.243 us; speedup vs baseline: 6.4013x; 2.7167x over previous
//
#include <hip/hip_runtime.h>
#include <hip/hip_bf16.h>
#include <math.h>

// Problem constants
#define B_   8
#define C_   256
#define P_   64
#define H_   64
#define W_   64
#define HW_  4096   // H_*W_

// Workspace layout (float units). Total ~119.94 MB. NO OVERLAPS:
//  TOPT_H [0,1048576) TOPT_L [1048576,2097152) CENT_H [..,3145728) CENT_L [..,4194304)
//  BOT [4194304,8388608) Y [8388608,16777216) XT_H [..,20971520) XT_L [..,25165824)
//  YT [..,29360128) WK1 [..,29655040) WK2 [..,29949952)
//  WTH [..,29958144) WTL [..,29966336) WCH [..,29974528) WCL [..,29982720)
//  PMAX [..,29983232) PSUM [..,29983744) MZ [..,29983760)
#define OFF_TOPT_H ((size_t)0)          // bf16 [b][m][p]
#define OFF_TOPT_L ((size_t)1048576)
#define OFF_CENT_H ((size_t)2097152)    // bf16 [b][n][p]
#define OFF_CENT_L ((size_t)3145728)
#define OFF_BOT    ((size_t)4194304)    // bf16 [b][c][m]
#define OFF_Y      ((size_t)8388608)    // fp32 [b][C*HW]
#define OFF_XT_H   ((size_t)16777216)   // bf16 [b][n][c]
#define OFF_XT_L   ((size_t)20971520)   // bf16 [b][n][c]
#define OFF_YT     ((size_t)25165824)   // bf16 [b][n][c]
#define OFF_WK1    ((size_t)29360128)   // bf16 [9][co][ci]
#define OFF_WK2    ((size_t)29655040)   // bf16 [9][co][ci]
#define OFF_WTH    ((size_t)29949952)   // bf16 [p][c] (16384 bf16 = 8192 f each)
#define OFF_WTL    ((size_t)29958144)
#define OFF_WCH    ((size_t)29966336)
#define OFF_WCL    ((size_t)29974528)
#define OFF_PMAX   ((size_t)29982720)   // fp32 [b][64]
#define OFF_PSUM   ((size_t)29983232)
#define OFF_MZ     ((size_t)29983744)

typedef __attribute__((ext_vector_type(8))) short bf16x8;
typedef __attribute__((ext_vector_type(4))) short bf16x4;
typedef __attribute__((ext_vector_type(4))) float f32x4;

static __device__ __forceinline__ short f2bf(float v) {
  __hip_bfloat16 h = __float2bfloat16(v);
  return *reinterpret_cast<short*>(&h);
}
static __device__ __forceinline__ float bf2f(short s) {
  __hip_bfloat16 h = *reinterpret_cast<__hip_bfloat16*>(&s);
  return __bfloat162float(h);
}

// Identical S-fragment sequence for pass1/pass2 (bitwise-consistent softmax).
static __device__ __forceinline__ f32x4 sfrag(
    bf16x8 ah0, bf16x8 al0, bf16x8 ah1, bf16x8 al1,
    bf16x8 bh0, bf16x8 bl0, bf16x8 bh1, bf16x8 bl1) {
  f32x4 s = (f32x4)0.f;
  s = __builtin_amdgcn_mfma_f32_16x16x32_bf16(al0, bh0, s, 0, 0, 0);
  s = __builtin_amdgcn_mfma_f32_16x16x32_bf16(ah0, bl0, s, 0, 0, 0);
  s = __builtin_amdgcn_mfma_f32_16x16x32_bf16(ah0, bh0, s, 0, 0, 0);
  s = __builtin_amdgcn_mfma_f32_16x16x32_bf16(al1, bh1, s, 0, 0, 0);
  s = __builtin_amdgcn_mfma_f32_16x16x32_bf16(ah1, bl1, s, 0, 0, 0);
  s = __builtin_amdgcn_mfma_f32_16x16x32_bf16(ah1, bh1, s, 0, 0, 0);
  return s;
}

// ---------------------------------------------------------------------------
// fp32 [b][C][HW] -> bf16 hi/lo [b][n][c]  (transpose + split)
__global__ __launch_bounds__(256) void pab_split_x(
    const float* __restrict__ in, __hip_bfloat16* __restrict__ hi,
    __hip_bfloat16* __restrict__ lo) {
  __shared__ float t[64][65];
  const int b = blockIdx.z, c0 = blockIdx.y * 64, n0 = blockIdx.x * 64;
  const int tid = threadIdx.x;
  const float* ib = in + ((size_t)b * C_ + c0) * HW_ + n0;
  for (int i = tid; i < 4096; i += 256) {
    const int c = i >> 6, n = i & 63;
    t[c][n] = ib[(size_t)c * HW_ + n];
  }
  __syncthreads();
  short* oh = (short*)hi + ((size_t)b * HW_ + n0) * C_ + c0;
  short* ol = (short*)lo + ((size_t)b * HW_ + n0) * C_ + c0;
  for (int i = tid; i < 4096; i += 256) {
    const int n = i >> 6, c = i & 63;
    const float v = t[c][n];
    const short h = f2bf(v);
    oh[(size_t)n * C_ + c] = h;
    ol[(size_t)n * C_ + c] = f2bf(v - bf2f(h));
  }
}

// fp32 [b][C][HW] -> bf16 [b][n][c] (transpose + convert, single precision)
__global__ __launch_bounds__(256) void pab_tcvt(
    const float* __restrict__ in, __hip_bfloat16* __restrict__ out) {
  __shared__ float t[64][65];
  const int b = blockIdx.z, c0 = blockIdx.y * 64, n0 = blockIdx.x * 64;
  const int tid = threadIdx.x;
  const float* ib = in + ((size_t)b * C_ + c0) * HW_ + n0;
  for (int i = tid; i < 4096; i += 256) {
    const int c = i >> 6, n = i & 63;
    t[c][n] = ib[(size_t)c * HW_ + n];
  }
  __syncthreads();
  __hip_bfloat16* ob = out + ((size_t)b * HW_ + n0) * C_ + c0;
  for (int i = tid; i < 4096; i += 256) {
    const int n = i >> 6, c = i & 63;
    ob[(size_t)n * C_ + c] = __float2bfloat16(t[c][n]);
  }
}

// 3x3 weights: fp32 [co][ci][9] -> bf16 [tap][co][ci]
__global__ __launch_bounds__(256) void pab_repack_w3(
    const float* __restrict__ w, __hip_bfloat16* __restrict__ out) {
  const int idx = blockIdx.x * 256 + threadIdx.x;
  const int co  = idx / 2304;
  const int rem = idx - co * 2304;
  const int ci  = rem / 9;
  const int k   = rem - ci * 9;
  out[((size_t)k * C_ + co) * C_ + ci] = __float2bfloat16(w[idx]);
}

// 1x1 weights: fp32 [p][c] -> bf16 hi/lo [p][c]
__global__ __launch_bounds__(256) void pab_split_w1(
    const float* __restrict__ w, __hip_bfloat16* __restrict__ hi,
    __hip_bfloat16* __restrict__ lo) {
  const int i = blockIdx.x * 256 + threadIdx.x;  // < 16384
  const float v = w[i];
  const short h = f2bf(v);
  ((short*)hi)[i] = h;
  ((short*)lo)[i] = f2bf(v - bf2f(h));
}

// ---------------------------------------------------------------------------
// 1x1 conv as split-bf16 MFMA GEMM; output transposed hi/lo [b][m][p].
__global__ __launch_bounds__(256) void pab_conv1x1_mfma(
    const __hip_bfloat16* __restrict__ xh, const __hip_bfloat16* __restrict__ xl,
    const __hip_bfloat16* __restrict__ wh, const __hip_bfloat16* __restrict__ wl,
    const float* __restrict__ bias,
    __hip_bfloat16* __restrict__ oh, __hip_bfloat16* __restrict__ ol) {
  const int b = blockIdx.y;
  const int tid = threadIdx.x, lane = tid & 63, wv = tid >> 6;
  const int nl = lane & 15, kg = lane >> 4;
  const int m0 = blockIdx.x * 256 + wv * 64;
  const short* xhs = (const short*)xh + (size_t)b * HW_ * C_;
  const short* xls = (const short*)xl + (size_t)b * HW_ * C_;
  const short* whs = (const short*)wh;
  const short* wls = (const short*)wl;
  f32x4 acc[4][4];
#pragma unroll
  for (int i = 0; i < 4; ++i)
#pragma unroll
    for (int j = 0; j < 4; ++j) acc[i][j] = (f32x4)0.f;

  for (int ci0 = 0; ci0 < C_; ci0 += 32) {
    bf16x8 ah[4], al[4], bh[4], bl[4];
#pragma unroll
    for (int i = 0; i < 4; ++i) {
      ah[i] = *(const bf16x8*)(whs + (size_t)(i * 16 + nl) * C_ + ci0 + kg * 8);
      al[i] = *(const bf16x8*)(wls + (size_t)(i * 16 + nl) * C_ + ci0 + kg * 8);
    }
#pragma unroll
    for (int j = 0; j < 4; ++j) {
      bh[j] = *(const bf16x8*)(xhs + (size_t)(m0 + j * 16 + nl) * C_ + ci0 + kg * 8);
      bl[j] = *(const bf16x8*)(xls + (size_t)(m0 + j * 16 + nl) * C_ + ci0 + kg * 8);
    }
#pragma unroll
    for (int i = 0; i < 4; ++i)
#pragma unroll
      for (int j = 0; j < 4; ++j) {
        acc[i][j] = __builtin_amdgcn_mfma_f32_16x16x32_bf16(al[i], bh[j], acc[i][j], 0, 0, 0);
        acc[i][j] = __builtin_amdgcn_mfma_f32_16x16x32_bf16(ah[i], bl[j], acc[i][j], 0, 0, 0);
        acc[i][j] = __builtin_amdgcn_mfma_f32_16x16x32_bf16(ah[i], bh[j], acc[i][j], 0, 0, 0);
      }
  }
  short* ohs = (short*)oh;
  short* ols = (short*)ol;
#pragma unroll
  for (int i = 0; i < 4; ++i)
#pragma unroll
    for (int j = 0; j < 4; ++j) {
      const int p0 = i * 16 + kg * 4;
      const int m  = m0 + j * 16 + nl;
      bf16x4 hv, lv;
#pragma unroll
      for (int r = 0; r < 4; ++r) {
        const float v = acc[i][j][r] + bias[p0 + r];
        const short h = f2bf(v);
        hv[r] = h;
        lv[r] = f2bf(v - bf2f(h));
      }
      const size_t base = ((size_t)b * HW_ + m) * P_ + p0;
      *(bf16x4*)(ohs + base) = hv;
      *(bf16x4*)(ols + base) = lv;
    }
}

// ---------------------------------------------------------------------------
// 3x3 conv as implicit GEMM with MFMA (bf16 in, fp32 accum).
// obf==0: fp32 out [b][co][n]; obf==1: bf16 out [b][co][n].
__global__ __launch_bounds__(256) void pab_conv3x3_mfma(
    const __hip_bfloat16* __restrict__ xT, const __hip_bfloat16* __restrict__ wk,
    const float* __restrict__ bias, float* __restrict__ outf,
    __hip_bfloat16* __restrict__ outb, const int obf) {
  __shared__ float lds[4][64][65];
  const int b   = blockIdx.y;
  const int n0  = blockIdx.x * 64;  // one image row
  const int h0  = n0 >> 6;
  const int tid = threadIdx.x;
  const int lane = tid & 63;
  const int wv   = tid >> 6;
  const int nl   = lane & 15;
  const int kg   = lane >> 4;
  const int cobase = wv * 64;

  const short* xTb = (const short*)xT + (size_t)b * HW_ * C_;
  const short* wks = (const short*)wk;

  f32x4 acc[4][4];
#pragma unroll
  for (int i = 0; i < 4; ++i)
#pragma unroll
    for (int j = 0; j < 4; ++j) acc[i][j] = (f32x4)0.f;

  for (int tap = 0; tap < 9; ++tap) {
    const int dh = tap / 3 - 1, dw = tap % 3 - 1;
    const bool vh = (unsigned)(h0 + dh) < 64u;
    const int doff = dh * 64 + dw;
    bool val[4];
    const short* bp[4];
#pragma unroll
    for (int j = 0; j < 4; ++j) {
      const int w = j * 16 + nl;
      val[j] = vh && ((unsigned)(w + dw) < 64u);
      bp[j]  = xTb + (size_t)(n0 + w + doff) * C_ + kg * 8;
    }
    const short* ap = wks + (size_t)tap * C_ * C_ + (size_t)(cobase + nl) * C_ + kg * 8;
#pragma unroll 2
    for (int ci0 = 0; ci0 < C_; ci0 += 32) {
      bf16x8 a[4], bb[4];
#pragma unroll
      for (int i = 0; i < 4; ++i) a[i] = *(const bf16x8*)(ap + (size_t)i * 16 * C_ + ci0);
#pragma unroll
      for (int j = 0; j < 4; ++j)
        bb[j] = val[j] ? *(const bf16x8*)(bp[j] + ci0) : (bf16x8)(short)0;
#pragma unroll
      for (int i = 0; i < 4; ++i)
#pragma unroll
        for (int j = 0; j < 4; ++j)
          acc[i][j] = __builtin_amdgcn_mfma_f32_16x16x32_bf16(a[i], bb[j], acc[i][j], 0, 0, 0);
    }
  }
#pragma unroll
  for (int i = 0; i < 4; ++i) {
    const int co_l = i * 16 + kg * 4;
#pragma unroll
    for (int j = 0; j < 4; ++j)
#pragma unroll
      for (int r = 0; r < 4; ++r)
        lds[wv][co_l + r][j * 16 + nl] = acc[i][j][r];
  }
  __syncthreads();
  if (obf) {
#pragma unroll 4
    for (int row = 0; row < 64; ++row) {
      const int co = cobase + row;
      outb[((size_t)b * C_ + co) * HW_ + n0 + lane] =
          __float2bfloat16(lds[wv][row][lane] + bias[co]);
    }
  } else {
#pragma unroll 4
    for (int row = 0; row < 64; ++row) {
      const int co = cobase + row;
      outf[((size_t)b * C_ + co) * HW_ + n0 + lane] = lds[wv][row][lane] + bias[co];
    }
  }
}

// ---------------------------------------------------------------------------
// Pass 1: global-softmax stats via split-bf16 MFMA scores.
__global__ __launch_bounds__(256) void pab_pass1_mfma(
    const __hip_bfloat16* __restrict__ cenh, const __hip_bfloat16* __restrict__ cenl,
    const __hip_bfloat16* __restrict__ toph, const __hip_bfloat16* __restrict__ topl,
    float* __restrict__ pmax, float* __restrict__ psum) {
  const int bid = blockIdx.x;
  const int b = bid & 7;           // batch == XCD (L2 affinity)
  const int n0 = (bid >> 3) * 64;
  const int tid = threadIdx.x, lane = tid & 63, wv = tid >> 6;
  const int nl = lane & 15, kg = lane >> 4;
  const short* ch = (const short*)cenh + ((size_t)b * HW_ + n0) * P_;
  const short* cl = (const short*)cenl + ((size_t)b * HW_ + n0) * P_;
  const short* th = (const short*)toph + (size_t)b * HW_ * P_;
  const short* tl = (const short*)topl + (size_t)b * HW_ * P_;
  bf16x8 cah[4][2], cal[4][2];
#pragma unroll
  for (int i = 0; i < 4; ++i)
#pragma unroll
    for (int ks = 0; ks < 2; ++ks) {
      cah[i][ks] = *(const bf16x8*)(ch + (size_t)(i * 16 + nl) * P_ + ks * 32 + kg * 8);
      cal[i][ks] = *(const bf16x8*)(cl + (size_t)(i * 16 + nl) * P_ + ks * 32 + kg * 8);
    }
  float mx = -3.0e38f, sm = 0.f;
  for (int t = 0; t < 64; ++t) {
    const int m = t * 64 + wv * 16;
    bf16x8 bh[2], bl[2];
#pragma unroll
    for (int ks = 0; ks < 2; ++ks) {
      bh[ks] = *(const bf16x8*)(th + (size_t)(m + nl) * P_ + ks * 32 + kg * 8);
      bl[ks] = *(const bf16x8*)(tl + (size_t)(m + nl) * P_ + ks * 32 + kg * 8);
    }
#pragma unroll
    for (int i = 0; i < 4; ++i) {
      f32x4 s = sfrag(cah[i][0], cal[i][0], cah[i][1], cal[i][1],
                      bh[0], bl[0], bh[1], bl[1]);
#pragma unroll
      for (int r = 0; r < 4; ++r) {
        const float v = s[r];
        if (v > mx) { sm = sm * __expf(mx - v) + 1.f; mx = v; }
        else        { sm += __expf(v - mx); }
      }
    }
  }
  __shared__ float rm[256], rs[256];
  rm[tid] = mx; rs[tid] = sm;
  __syncthreads();
  for (int off = 128; off > 0; off >>= 1) {
    if (tid < off) {
      const float m1 = rm[tid], s1 = rs[tid];
      const float m2 = rm[tid + off], s2 = rs[tid + off];
      const float M = fmaxf(m1, m2);
      rm[tid] = M;
      rs[tid] = s1 * __expf(m1 - M) + s2 * __expf(m2 - M);
    }
    __syncthreads();
  }
  if (tid == 0) {
    pmax[b * 64 + (bid >> 3)] = rm[0];
    psum[b * 64 + (bid >> 3)] = rs[0];
  }
}

// Combine 64 partials per batch -> global (M, Z)
__global__ __launch_bounds__(64) void pab_reduce64(
    const float* __restrict__ pmax, const float* __restrict__ psum,
    float* __restrict__ MZ) {
  const int b = blockIdx.x, tid = threadIdx.x;
  __shared__ float rm[64], rs[64];
  rm[tid] = pmax[b * 64 + tid];
  rs[tid] = psum[b * 64 + tid];
  __syncthreads();
  for (int off = 32; off > 0; off >>= 1) {
    if (tid < off) {
      const float m1 = rm[tid], s1 = rs[tid];
      const float m2 = rm[tid + off], s2 = rs[tid + off];
      const float M = fmaxf(m1, m2);
      rm[tid] = M;
      rs[tid] = s1 * __expf(m1 - M) + s2 * __expf(m2 - M);
    }
    __syncthreads();
  }
  if (tid == 0) { MZ[b * 2] = rm[0]; MZ[b * 2 + 1] = rs[0]; }
}

// ---------------------------------------------------------------------------
// Pass 2: flash-style apply. S (split-bf16 MFMA, identical to pass1) -> exp ->
// bf16 P in XOR-swizzled LDS -> PV MFMA vs bot[c][m] -> y = x + attn/Z (flat).
__global__ __launch_bounds__(256) void pab_pass2_mfma(
    const __hip_bfloat16* __restrict__ cenh, const __hip_bfloat16* __restrict__ cenl,
    const __hip_bfloat16* __restrict__ toph, const __hip_bfloat16* __restrict__ topl,
    const __hip_bfloat16* __restrict__ bot, const float* __restrict__ x,
    const float* __restrict__ MZ, float* __restrict__ y) {
  __shared__ __align__(16) char P_lds[8192];  // 64n x 64m bf16, swizzled
  const int bid = blockIdx.x;
  const int b = bid & 7;
  const int n0 = (bid >> 3) * 64;
  const int tid = threadIdx.x, lane = tid & 63, wv = tid >> 6;
  const int nl = lane & 15, kg = lane >> 4;
  const float Mg   = MZ[b * 2];
  const float invZ = 1.f / MZ[b * 2 + 1];
  const short* ch = (const short*)cenh + ((size_t)b * HW_ + n0) * P_;
  const short* cl = (const short*)cenl + ((size_t)b * HW_ + n0) * P_;
  const short* th = (const short*)toph + (size_t)b * HW_ * P_;
  const short* tl = (const short*)topl + (size_t)b * HW_ * P_;
  const short* botb = (const short*)bot + (size_t)b * C_ * HW_;

  bf16x8 cah[4][2], cal[4][2];
#pragma unroll
  for (int i = 0; i < 4; ++i)
#pragma unroll
    for (int ks = 0; ks < 2; ++ks) {
      cah[i][ks] = *(const bf16x8*)(ch + (size_t)(i * 16 + nl) * P_ + ks * 32 + kg * 8);
      cal[i][ks] = *(const bf16x8*)(cl + (size_t)(i * 16 + nl) * P_ + ks * 32 + kg * 8);
    }
  f32x4 acc[4][4];
#pragma unroll
  for (int i = 0; i < 4; ++i)
#pragma unroll
    for (int j = 0; j < 4; ++j) acc[i][j] = (f32x4)0.f;

  for (int t = 0; t < 64; ++t) {
    const int m0 = t * 64;
    {  // S phase: this wave's 16 m-cols
      const int m = m0 + wv * 16;
      bf16x8 bh[2], bl[2];
#pragma unroll
      for (int ks = 0; ks < 2; ++ks) {
        bh[ks] = *(const bf16x8*)(th + (size_t)(m + nl) * P_ + ks * 32 + kg * 8);
        bl[ks] = *(const bf16x8*)(tl + (size_t)(m + nl) * P_ + ks * 32 + kg * 8);
      }
#pragma unroll
      for (int i = 0; i < 4; ++i) {
        f32x4 s = sfrag(cah[i][0], cal[i][0], cah[i][1], cal[i][1],
                        bh[0], bl[0], bh[1], bl[1]);
#pragma unroll
        for (int r = 0; r < 4; ++r) {
          const int n = i * 16 + kg * 4 + r;
          const int ba = ((n * 64 + wv * 16 + nl) * 2) ^ ((n & 7) << 4);
          *(short*)(P_lds + ba) = f2bf(__expf(s[r] - Mg));
        }
      }
    }
    __syncthreads();
    {  // PV phase: A = P_lds (all 64n), B = bot c-slice [wv*64, +64)
      bf16x8 pa[4][2];
#pragma unroll
      for (int i = 0; i < 4; ++i)
#pragma unroll
        for (int ks = 0; ks < 2; ++ks) {
          const int n = i * 16 + nl;
          const int ra = (n * 128 + ks * 64 + kg * 16) ^ ((n & 7) << 4);
          pa[i][ks] = *(const bf16x8*)(P_lds + ra);
        }
#pragma unroll
      for (int j = 0; j < 4; ++j) {
        const size_t cb = (size_t)(wv * 64 + j * 16 + nl) * HW_ + m0 + kg * 8;
        const bf16x8 b0 = *(const bf16x8*)(botb + cb);
        const bf16x8 b1 = *(const bf16x8*)(botb + cb + 32);
#pragma unroll
        for (int i = 0; i < 4; ++i) {
          acc[i][j] = __builtin_amdgcn_mfma_f32_16x16x32_bf16(pa[i][0], b0, acc[i][j], 0, 0, 0);
          acc[i][j] = __builtin_amdgcn_mfma_f32_16x16x32_bf16(pa[i][1], b1, acc[i][j], 0, 0, 0);
        }
      }
    }
    __syncthreads();
  }
  // epilogue: y flat(n*C+c) = x flat + attn/Z  (reshape semantics)
  const size_t xb = (size_t)b * (size_t)C_ * HW_;
#pragma unroll
  for (int i = 0; i < 4; ++i)
#pragma unroll
    for (int j = 0; j < 4; ++j) {
      const int c = wv * 64 + j * 16 + nl;
#pragma unroll
      for (int r = 0; r < 4; ++r) {
        const int n = n0 + i * 16 + kg * 4 + r;
        const size_t flat = (size_t)n * C_ + c;
        y[xb + flat] = x[xb + flat] + acc[i][j][r] * invZ;
      }
    }
}

// ---------------------------------------------------------------------------
extern "C" void kernel_launch(void* const* d_in, const int* in_sizes, int n_in,
                              void* d_out, int out_size, void* d_ws, size_t ws_size,
                              hipStream_t stream) {
  const float* x        = (const float*)d_in[0];
  const float* top_w    = (const float*)d_in[1];
  const float* top_b    = (const float*)d_in[2];
  const float* center_w = (const float*)d_in[3];
  const float* center_b = (const float*)d_in[4];
  const float* bottom_w = (const float*)d_in[5];
  const float* bottom_b = (const float*)d_in[6];
  const float* out_w    = (const float*)d_in[7];
  const float* out_b    = (const float*)d_in[8];
  float* ws = (float*)d_ws;
  __hip_bfloat16* w_topth = (__hip_bfloat16*)(ws + OFF_TOPT_H);
  __hip_bfloat16* w_toptl = (__hip_bfloat16*)(ws + OFF_TOPT_L);
  __hip_bfloat16* w_centh = (__hip_bfloat16*)(ws + OFF_CENT_H);
  __hip_bfloat16* w_centl = (__hip_bfloat16*)(ws + OFF_CENT_L);
  __hip_bfloat16* w_bot   = (__hip_bfloat16*)(ws + OFF_BOT);
  float*          w_y     = ws + OFF_Y;
  __hip_bfloat16* w_xth   = (__hip_bfloat16*)(ws + OFF_XT_H);
  __hip_bfloat16* w_xtl   = (__hip_bfloat16*)(ws + OFF_XT_L);
  __hip_bfloat16* w_yt    = (__hip_bfloat16*)(ws + OFF_YT);
  __hip_bfloat16* w_wk1   = (__hip_bfloat16*)(ws + OFF_WK1);
  __hip_bfloat16* w_wk2   = (__hip_bfloat16*)(ws + OFF_WK2);
  __hip_bfloat16* w_wth   = (__hip_bfloat16*)(ws + OFF_WTH);
  __hip_bfloat16* w_wtl   = (__hip_bfloat16*)(ws + OFF_WTL);
  __hip_bfloat16* w_wch   = (__hip_bfloat16*)(ws + OFF_WCH);
  __hip_bfloat16* w_wcl   = (__hip_bfloat16*)(ws + OFF_WCL);
  float* w_pmax = ws + OFF_PMAX;
  float* w_psum = ws + OFF_PSUM;
  float* w_MZ   = ws + OFF_MZ;
  (void)in_sizes; (void)n_in; (void)out_size; (void)ws_size;

  // prologue: splits/repacks
  pab_split_x<<<dim3(64, 4, 8), 256, 0, stream>>>(x, w_xth, w_xtl);
  pab_repack_w3<<<dim3(2304), 256, 0, stream>>>(bottom_w, w_wk1);
  pab_repack_w3<<<dim3(2304), 256, 0, stream>>>(out_w, w_wk2);
  pab_split_w1<<<dim3(64), 256, 0, stream>>>(top_w, w_wth, w_wtl);
  pab_split_w1<<<dim3(64), 256, 0, stream>>>(center_w, w_wch, w_wcl);

  // 1x1 convs (split-bf16 MFMA) -> transposed hi/lo [m][p]
  pab_conv1x1_mfma<<<dim3(16, 8), 256, 0, stream>>>(w_xth, w_xtl, w_wth, w_wtl,
                                                    top_b, w_topth, w_toptl);
  pab_conv1x1_mfma<<<dim3(16, 8), 256, 0, stream>>>(w_xth, w_xtl, w_wch, w_wcl,
                                                    center_b, w_centh, w_centl);
  // 3x3 conv -> bot bf16 [c][m]
  pab_conv3x3_mfma<<<dim3(64, 8), 256, 0, stream>>>(w_xth, w_wk1, bottom_b,
                                                    (float*)nullptr, w_bot, 1);
  // global-softmax stats
  pab_pass1_mfma<<<dim3(512), 256, 0, stream>>>(w_centh, w_centl, w_topth, w_toptl,
                                                w_pmax, w_psum);
  pab_reduce64<<<dim3(8), 64, 0, stream>>>(w_pmax, w_psum, w_MZ);
  // attention apply + residual
  pab_pass2_mfma<<<dim3(512), 256, 0, stream>>>(w_centh, w_centl, w_topth, w_toptl,
                                                w_bot, x, w_MZ, w_y);
  // final 3x3 conv
  pab_tcvt<<<dim3(64, 4, 8), 256, 0, stream>>>(w_y, w_yt);
  pab_conv3x3_mfma<<<dim3(64, 8), 256, 0, stream>>>(w_yt, w_wk2, out_b,
                                                    (float*)d_out, (__hip_bfloat16*)nullptr, 0);
}

// Round 6
// 633.938 us; speedup vs baseline: 7.7675x; 1.2134x over previous
//
#include <hip/hip_runtime.h>
#include <hip/hip_bf16.h>
#include <math.h>

// Problem constants
#define B_   8
#define C_   256
#define P_   64
#define H_   64
#define W_   64
#define HW_  4096   // H_*W_

// Workspace layout (float units). Total ~119.94 MB. NO OVERLAPS.
#define OFF_TOPT_H ((size_t)0)          // bf16 [b][m][p]
#define OFF_TOPT_L ((size_t)1048576)
#define OFF_CENT_H ((size_t)2097152)    // bf16 [b][n][p]
#define OFF_CENT_L ((size_t)3145728)
#define OFF_BOT    ((size_t)4194304)    // bf16 [b][c][m]
#define OFF_ATTN   ((size_t)8388608)    // fp32 [b][C*HW] unnormalized attention
#define OFF_XT_H   ((size_t)16777216)   // bf16 [b][n][c]
#define OFF_XT_L   ((size_t)20971520)   // bf16 [b][n][c]
#define OFF_YT     ((size_t)25165824)   // bf16 [b][n][c]
#define OFF_WK1    ((size_t)29360128)   // bf16 [9][co][ci]
#define OFF_WK2    ((size_t)29655040)   // bf16 [9][co][ci]
#define OFF_WTH    ((size_t)29949952)   // bf16 [p][c] (8192 f each)
#define OFF_WTL    ((size_t)29958144)
#define OFF_WCH    ((size_t)29966336)
#define OFF_WCL    ((size_t)29974528)
#define OFF_PMAX   ((size_t)29982720)   // fp32 [b][64]
#define OFF_ZPART  ((size_t)29983232)   // fp32 [b][64]
#define OFF_MZ     ((size_t)29983744)   // fp32 [b][2] : M, Z

typedef __attribute__((ext_vector_type(8))) short bf16x8;
typedef __attribute__((ext_vector_type(4))) short bf16x4;
typedef __attribute__((ext_vector_type(4))) float f32x4;

static __device__ __forceinline__ short f2bf(float v) {
  __hip_bfloat16 h = __float2bfloat16(v);
  return *reinterpret_cast<short*>(&h);
}
static __device__ __forceinline__ float bf2f(short s) {
  __hip_bfloat16 h = *reinterpret_cast<__hip_bfloat16*>(&s);
  return __bfloat162float(h);
}

// Split-bf16 S-fragment (hi/lo, 3 cross terms).
static __device__ __forceinline__ f32x4 sfrag(
    bf16x8 ah0, bf16x8 al0, bf16x8 ah1, bf16x8 al1,
    bf16x8 bh0, bf16x8 bl0, bf16x8 bh1, bf16x8 bl1) {
  f32x4 s = (f32x4)0.f;
  s = __builtin_amdgcn_mfma_f32_16x16x32_bf16(al0, bh0, s, 0, 0, 0);
  s = __builtin_amdgcn_mfma_f32_16x16x32_bf16(ah0, bl0, s, 0, 0, 0);
  s = __builtin_amdgcn_mfma_f32_16x16x32_bf16(ah0, bh0, s, 0, 0, 0);
  s = __builtin_amdgcn_mfma_f32_16x16x32_bf16(al1, bh1, s, 0, 0, 0);
  s = __builtin_amdgcn_mfma_f32_16x16x32_bf16(ah1, bl1, s, 0, 0, 0);
  s = __builtin_amdgcn_mfma_f32_16x16x32_bf16(ah1, bh1, s, 0, 0, 0);
  return s;
}

// ---------------------------------------------------------------------------
// fp32 [b][C][HW] -> bf16 hi/lo [b][n][c]  (transpose + split)
__global__ __launch_bounds__(256) void pab_split_x(
    const float* __restrict__ in, __hip_bfloat16* __restrict__ hi,
    __hip_bfloat16* __restrict__ lo) {
  __shared__ float t[64][65];
  const int b = blockIdx.z, c0 = blockIdx.y * 64, n0 = blockIdx.x * 64;
  const int tid = threadIdx.x;
  const float* ib = in + ((size_t)b * C_ + c0) * HW_ + n0;
  for (int i = tid; i < 4096; i += 256) {
    const int c = i >> 6, n = i & 63;
    t[c][n] = ib[(size_t)c * HW_ + n];
  }
  __syncthreads();
  short* oh = (short*)hi + ((size_t)b * HW_ + n0) * C_ + c0;
  short* ol = (short*)lo + ((size_t)b * HW_ + n0) * C_ + c0;
  for (int i = tid; i < 4096; i += 256) {
    const int n = i >> 6, c = i & 63;
    const float v = t[c][n];
    const short h = f2bf(v);
    oh[(size_t)n * C_ + c] = h;
    ol[(size_t)n * C_ + c] = f2bf(v - bf2f(h));
  }
}

// fused: y = x + attn*invZ (flat reshape), then transpose -> bf16 [b][n][c]
__global__ __launch_bounds__(256) void pab_tcvt2(
    const float* __restrict__ x, const float* __restrict__ attn,
    const float* __restrict__ MZ, __hip_bfloat16* __restrict__ out) {
  __shared__ float t[64][65];
  const int b = blockIdx.z, c0 = blockIdx.y * 64, n0 = blockIdx.x * 64;
  const int tid = threadIdx.x;
  const float invZ = 1.f / MZ[b * 2 + 1];
  const float* xb = x + ((size_t)b * C_ + c0) * HW_ + n0;
  const float* ab = attn + ((size_t)b * C_ + c0) * HW_ + n0;  // same flat view
  for (int i = tid; i < 4096; i += 256) {
    const int c = i >> 6, n = i & 63;
    t[c][n] = xb[(size_t)c * HW_ + n] + ab[(size_t)c * HW_ + n] * invZ;
  }
  __syncthreads();
  __hip_bfloat16* ob = out + ((size_t)b * HW_ + n0) * C_ + c0;
  for (int i = tid; i < 4096; i += 256) {
    const int n = i >> 6, c = i & 63;
    ob[(size_t)n * C_ + c] = __float2bfloat16(t[c][n]);
  }
}

// 3x3 weights: fp32 [co][ci][9] -> bf16 [tap][co][ci]
__global__ __launch_bounds__(256) void pab_repack_w3(
    const float* __restrict__ w, __hip_bfloat16* __restrict__ out) {
  const int idx = blockIdx.x * 256 + threadIdx.x;
  const int co  = idx / 2304;
  const int rem = idx - co * 2304;
  const int ci  = rem / 9;
  const int k   = rem - ci * 9;
  out[((size_t)k * C_ + co) * C_ + ci] = __float2bfloat16(w[idx]);
}

// 1x1 weights: fp32 [p][c] -> bf16 hi/lo [p][c]
__global__ __launch_bounds__(256) void pab_split_w1(
    const float* __restrict__ w, __hip_bfloat16* __restrict__ hi,
    __hip_bfloat16* __restrict__ lo) {
  const int i = blockIdx.x * 256 + threadIdx.x;  // < 16384
  const float v = w[i];
  const short h = f2bf(v);
  ((short*)hi)[i] = h;
  ((short*)lo)[i] = f2bf(v - bf2f(h));
}

// ---------------------------------------------------------------------------
// 1x1 conv as split-bf16 MFMA GEMM; output transposed hi/lo [b][m][p].
__global__ __launch_bounds__(256) void pab_conv1x1_mfma(
    const __hip_bfloat16* __restrict__ xh, const __hip_bfloat16* __restrict__ xl,
    const __hip_bfloat16* __restrict__ wh, const __hip_bfloat16* __restrict__ wl,
    const float* __restrict__ bias,
    __hip_bfloat16* __restrict__ oh, __hip_bfloat16* __restrict__ ol) {
  const int b = blockIdx.y;
  const int tid = threadIdx.x, lane = tid & 63, wv = tid >> 6;
  const int nl = lane & 15, kg = lane >> 4;
  const int m0 = blockIdx.x * 256 + wv * 64;
  const short* xhs = (const short*)xh + (size_t)b * HW_ * C_;
  const short* xls = (const short*)xl + (size_t)b * HW_ * C_;
  const short* whs = (const short*)wh;
  const short* wls = (const short*)wl;
  f32x4 acc[4][4];
#pragma unroll
  for (int i = 0; i < 4; ++i)
#pragma unroll
    for (int j = 0; j < 4; ++j) acc[i][j] = (f32x4)0.f;

  for (int ci0 = 0; ci0 < C_; ci0 += 32) {
    bf16x8 ah[4], al[4], bh[4], bl[4];
#pragma unroll
    for (int i = 0; i < 4; ++i) {
      ah[i] = *(const bf16x8*)(whs + (size_t)(i * 16 + nl) * C_ + ci0 + kg * 8);
      al[i] = *(const bf16x8*)(wls + (size_t)(i * 16 + nl) * C_ + ci0 + kg * 8);
    }
#pragma unroll
    for (int j = 0; j < 4; ++j) {
      bh[j] = *(const bf16x8*)(xhs + (size_t)(m0 + j * 16 + nl) * C_ + ci0 + kg * 8);
      bl[j] = *(const bf16x8*)(xls + (size_t)(m0 + j * 16 + nl) * C_ + ci0 + kg * 8);
    }
#pragma unroll
    for (int i = 0; i < 4; ++i)
#pragma unroll
      for (int j = 0; j < 4; ++j) {
        acc[i][j] = __builtin_amdgcn_mfma_f32_16x16x32_bf16(al[i], bh[j], acc[i][j], 0, 0, 0);
        acc[i][j] = __builtin_amdgcn_mfma_f32_16x16x32_bf16(ah[i], bl[j], acc[i][j], 0, 0, 0);
        acc[i][j] = __builtin_amdgcn_mfma_f32_16x16x32_bf16(ah[i], bh[j], acc[i][j], 0, 0, 0);
      }
  }
  short* ohs = (short*)oh;
  short* ols = (short*)ol;
#pragma unroll
  for (int i = 0; i < 4; ++i)
#pragma unroll
    for (int j = 0; j < 4; ++j) {
      const int p0 = i * 16 + kg * 4;
      const int m  = m0 + j * 16 + nl;
      bf16x4 hv, lv;
#pragma unroll
      for (int r = 0; r < 4; ++r) {
        const float v = acc[i][j][r] + bias[p0 + r];
        const short h = f2bf(v);
        hv[r] = h;
        lv[r] = f2bf(v - bf2f(h));
      }
      const size_t base = ((size_t)b * HW_ + m) * P_ + p0;
      *(bf16x4*)(ohs + base) = hv;
      *(bf16x4*)(ols + base) = lv;
    }
}

// ---------------------------------------------------------------------------
// 3x3 conv as implicit GEMM with MFMA (bf16 in, fp32 accum).
// obf==0: fp32 out [b][co][n]; obf==1: bf16 out [b][co][n].
__global__ __launch_bounds__(256) void pab_conv3x3_mfma(
    const __hip_bfloat16* __restrict__ xT, const __hip_bfloat16* __restrict__ wk,
    const float* __restrict__ bias, float* __restrict__ outf,
    __hip_bfloat16* __restrict__ outb, const int obf) {
  __shared__ float lds[4][64][65];
  const int b   = blockIdx.y;
  const int n0  = blockIdx.x * 64;  // one image row
  const int h0  = n0 >> 6;
  const int tid = threadIdx.x;
  const int lane = tid & 63;
  const int wv   = tid >> 6;
  const int nl   = lane & 15;
  const int kg   = lane >> 4;
  const int cobase = wv * 64;

  const short* xTb = (const short*)xT + (size_t)b * HW_ * C_;
  const short* wks = (const short*)wk;

  f32x4 acc[4][4];
#pragma unroll
  for (int i = 0; i < 4; ++i)
#pragma unroll
    for (int j = 0; j < 4; ++j) acc[i][j] = (f32x4)0.f;

  for (int tap = 0; tap < 9; ++tap) {
    const int dh = tap / 3 - 1, dw = tap % 3 - 1;
    const bool vh = (unsigned)(h0 + dh) < 64u;
    const int doff = dh * 64 + dw;
    bool val[4];
    const short* bp[4];
#pragma unroll
    for (int j = 0; j < 4; ++j) {
      const int w = j * 16 + nl;
      val[j] = vh && ((unsigned)(w + dw) < 64u);
      bp[j]  = xTb + (size_t)(n0 + w + doff) * C_ + kg * 8;
    }
    const short* ap = wks + (size_t)tap * C_ * C_ + (size_t)(cobase + nl) * C_ + kg * 8;
#pragma unroll 2
    for (int ci0 = 0; ci0 < C_; ci0 += 32) {
      bf16x8 a[4], bb[4];
#pragma unroll
      for (int i = 0; i < 4; ++i) a[i] = *(const bf16x8*)(ap + (size_t)i * 16 * C_ + ci0);
#pragma unroll
      for (int j = 0; j < 4; ++j)
        bb[j] = val[j] ? *(const bf16x8*)(bp[j] + ci0) : (bf16x8)(short)0;
#pragma unroll
      for (int i = 0; i < 4; ++i)
#pragma unroll
        for (int j = 0; j < 4; ++j)
          acc[i][j] = __builtin_amdgcn_mfma_f32_16x16x32_bf16(a[i], bb[j], acc[i][j], 0, 0, 0);
    }
  }
#pragma unroll
  for (int i = 0; i < 4; ++i) {
    const int co_l = i * 16 + kg * 4;
#pragma unroll
    for (int j = 0; j < 4; ++j)
#pragma unroll
      for (int r = 0; r < 4; ++r)
        lds[wv][co_l + r][j * 16 + nl] = acc[i][j][r];
  }
  __syncthreads();
  if (obf) {
#pragma unroll 4
    for (int row = 0; row < 64; ++row) {
      const int co = cobase + row;
      outb[((size_t)b * C_ + co) * HW_ + n0 + lane] =
          __float2bfloat16(lds[wv][row][lane] + bias[co]);
    }
  } else {
#pragma unroll 4
    for (int row = 0; row < 64; ++row) {
      const int co = cobase + row;
      outf[((size_t)b * C_ + co) * HW_ + n0 + lane] = lds[wv][row][lane] + bias[co];
    }
  }
}

// ---------------------------------------------------------------------------
// Pass 1 (max only): 1-term bf16 S. M only needs to be near the true max —
// exact softmax math holds for ANY M; p = exp(s-M) stays <= ~e^0.2.
__global__ __launch_bounds__(256) void pab_pass1max(
    const __hip_bfloat16* __restrict__ cenh, const __hip_bfloat16* __restrict__ toph,
    float* __restrict__ pmax) {
  __shared__ float ms[4];
  const int bid = blockIdx.x;
  const int b = bid & 7;           // batch == XCD (L2 affinity)
  const int n0 = (bid >> 3) * 64;
  const int tid = threadIdx.x, lane = tid & 63, wv = tid >> 6;
  const int nl = lane & 15, kg = lane >> 4;
  const short* ch = (const short*)cenh + ((size_t)b * HW_ + n0) * P_;
  const short* th = (const short*)toph + (size_t)b * HW_ * P_;
  bf16x8 cah[4][2];
#pragma unroll
  for (int i = 0; i < 4; ++i)
#pragma unroll
    for (int ks = 0; ks < 2; ++ks)
      cah[i][ks] = *(const bf16x8*)(ch + (size_t)(i * 16 + nl) * P_ + ks * 32 + kg * 8);
  float mx = -3.0e38f;
  for (int t = 0; t < 64; ++t) {
    const int m = t * 64 + wv * 16;
    const bf16x8 bh0 = *(const bf16x8*)(th + (size_t)(m + nl) * P_ + kg * 8);
    const bf16x8 bh1 = *(const bf16x8*)(th + (size_t)(m + nl) * P_ + 32 + kg * 8);
#pragma unroll
    for (int i = 0; i < 4; ++i) {
      f32x4 s = (f32x4)0.f;
      s = __builtin_amdgcn_mfma_f32_16x16x32_bf16(cah[i][0], bh0, s, 0, 0, 0);
      s = __builtin_amdgcn_mfma_f32_16x16x32_bf16(cah[i][1], bh1, s, 0, 0, 0);
      mx = fmaxf(mx, fmaxf(fmaxf(s[0], s[1]), fmaxf(s[2], s[3])));
    }
  }
#pragma unroll
  for (int off = 32; off > 0; off >>= 1) mx = fmaxf(mx, __shfl_down(mx, off));
  if (lane == 0) ms[wv] = mx;
  __syncthreads();
  if (tid == 0)
    pmax[b * 64 + (bid >> 3)] = fmaxf(fmaxf(ms[0], ms[1]), fmaxf(ms[2], ms[3]));
}

// 64 partial maxes -> M per batch
__global__ __launch_bounds__(64) void pab_reduceM(
    const float* __restrict__ pmax, float* __restrict__ MZ) {
  const int b = blockIdx.x;
  float v = pmax[b * 64 + threadIdx.x];
#pragma unroll
  for (int off = 32; off > 0; off >>= 1) v = fmaxf(v, __shfl_down(v, off));
  if (threadIdx.x == 0) MZ[b * 2] = v;
}

// 64 partial sums -> Z per batch (deterministic tree order)
__global__ __launch_bounds__(64) void pab_reduceZ(
    const float* __restrict__ zpart, float* __restrict__ MZ) {
  const int b = blockIdx.x;
  float v = zpart[b * 64 + threadIdx.x];
#pragma unroll
  for (int off = 32; off > 0; off >>= 1) v += __shfl_down(v, off);
  if (threadIdx.x == 0) MZ[b * 2 + 1] = v;
}

// ---------------------------------------------------------------------------
// Pass 2: double-buffered flash apply. Per iter: S(t+1)->buf^1 overlapped with
// PV(t) from buf, ONE barrier. Also accumulates Z (sum of bf16-rounded p,
// consistent with what PV consumes). Writes UNNORMALIZED attn (fp32).
__global__ __launch_bounds__(256) void pab_pass2_mfma(
    const __hip_bfloat16* __restrict__ cenh, const __hip_bfloat16* __restrict__ cenl,
    const __hip_bfloat16* __restrict__ toph, const __hip_bfloat16* __restrict__ topl,
    const __hip_bfloat16* __restrict__ bot, const float* __restrict__ MZ,
    float* __restrict__ attn, float* __restrict__ zpart) {
  __shared__ __align__(16) char P_lds[2][8192];  // 64n x 64m bf16, swizzled
  const int bid = blockIdx.x;
  const int b = bid & 7;
  const int n0 = (bid >> 3) * 64;
  const int tid = threadIdx.x, lane = tid & 63, wv = tid >> 6;
  const int nl = lane & 15, kg = lane >> 4;
  const float Mg = MZ[b * 2];
  const short* ch = (const short*)cenh + ((size_t)b * HW_ + n0) * P_;
  const short* cl = (const short*)cenl + ((size_t)b * HW_ + n0) * P_;
  const short* th = (const short*)toph + (size_t)b * HW_ * P_;
  const short* tl = (const short*)topl + (size_t)b * HW_ * P_;
  const short* botb = (const short*)bot + (size_t)b * C_ * HW_;

  bf16x8 cah[4][2], cal[4][2];
#pragma unroll
  for (int i = 0; i < 4; ++i)
#pragma unroll
    for (int ks = 0; ks < 2; ++ks) {
      cah[i][ks] = *(const bf16x8*)(ch + (size_t)(i * 16 + nl) * P_ + ks * 32 + kg * 8);
      cal[i][ks] = *(const bf16x8*)(cl + (size_t)(i * 16 + nl) * P_ + ks * 32 + kg * 8);
    }
  f32x4 acc[4][4];
#pragma unroll
  for (int i = 0; i < 4; ++i)
#pragma unroll
    for (int j = 0; j < 4; ++j) acc[i][j] = (f32x4)0.f;
  float zacc = 0.f;

  // S phase for tile tt -> bufp (this wave's 16 m-cols), accumulating Z.
  auto S_body = [&](int tt, char* bufp) {
    const int m = tt * 64 + wv * 16;
    bf16x8 bh[2], bl[2];
#pragma unroll
    for (int ks = 0; ks < 2; ++ks) {
      bh[ks] = *(const bf16x8*)(th + (size_t)(m + nl) * P_ + ks * 32 + kg * 8);
      bl[ks] = *(const bf16x8*)(tl + (size_t)(m + nl) * P_ + ks * 32 + kg * 8);
    }
#pragma unroll
    for (int i = 0; i < 4; ++i) {
      f32x4 s = sfrag(cah[i][0], cal[i][0], cah[i][1], cal[i][1],
                      bh[0], bl[0], bh[1], bl[1]);
#pragma unroll
      for (int r = 0; r < 4; ++r) {
        const int n = i * 16 + kg * 4 + r;
        const short pb = f2bf(__expf(s[r] - Mg));
        zacc += bf2f(pb);
        const int ba = ((n * 64 + wv * 16 + nl) * 2) ^ ((n & 7) << 4);
        *(short*)(bufp + ba) = pb;
      }
    }
  };
  // PV phase for tile tt from bufp (A = full P tile, B = bot c-slice).
  auto PV_body = [&](int tt, const char* bufp) {
    bf16x8 pa[4][2];
#pragma unroll
    for (int i = 0; i < 4; ++i)
#pragma unroll
      for (int ks = 0; ks < 2; ++ks) {
        const int n = i * 16 + nl;
        const int ra = (n * 128 + ks * 64 + kg * 16) ^ ((n & 7) << 4);
        pa[i][ks] = *(const bf16x8*)(bufp + ra);
      }
#pragma unroll
    for (int j = 0; j < 4; ++j) {
      const size_t cb = (size_t)(wv * 64 + j * 16 + nl) * HW_ + tt * 64 + kg * 8;
      const bf16x8 b0 = *(const bf16x8*)(botb + cb);
      const bf16x8 b1 = *(const bf16x8*)(botb + cb + 32);
#pragma unroll
      for (int i = 0; i < 4; ++i) {
        acc[i][j] = __builtin_amdgcn_mfma_f32_16x16x32_bf16(pa[i][0], b0, acc[i][j], 0, 0, 0);
        acc[i][j] = __builtin_amdgcn_mfma_f32_16x16x32_bf16(pa[i][1], b1, acc[i][j], 0, 0, 0);
      }
    }
  };

  S_body(0, P_lds[0]);
  __syncthreads();
  for (int t = 0; t < 64; ++t) {
    if (t < 63) S_body(t + 1, P_lds[(t + 1) & 1]);
    PV_body(t, P_lds[t & 1]);
    __syncthreads();
  }

  // epilogue: write unnormalized attn (flat n*C+c), reduce Z partial.
  float* attnb = attn + (size_t)b * (size_t)C_ * HW_;
#pragma unroll
  for (int i = 0; i < 4; ++i)
#pragma unroll
    for (int j = 0; j < 4; ++j) {
      const int c = wv * 64 + j * 16 + nl;
#pragma unroll
      for (int r = 0; r < 4; ++r) {
        const int n = n0 + i * 16 + kg * 4 + r;
        attnb[(size_t)n * C_ + c] = acc[i][j][r];
      }
    }
#pragma unroll
  for (int off = 32; off > 0; off >>= 1) zacc += __shfl_down(zacc, off);
  float* zsh = (float*)P_lds[0];
  if (lane == 0) zsh[wv] = zacc;
  __syncthreads();
  if (tid == 0)
    zpart[b * 64 + (bid >> 3)] = (zsh[0] + zsh[1]) + (zsh[2] + zsh[3]);
}

// ---------------------------------------------------------------------------
extern "C" void kernel_launch(void* const* d_in, const int* in_sizes, int n_in,
                              void* d_out, int out_size, void* d_ws, size_t ws_size,
                              hipStream_t stream) {
  const float* x        = (const float*)d_in[0];
  const float* top_w    = (const float*)d_in[1];
  const float* top_b    = (const float*)d_in[2];
  const float* center_w = (const float*)d_in[3];
  const float* center_b = (const float*)d_in[4];
  const float* bottom_w = (const float*)d_in[5];
  const float* bottom_b = (const float*)d_in[6];
  const float* out_w    = (const float*)d_in[7];
  const float* out_b    = (const float*)d_in[8];
  float* ws = (float*)d_ws;
  __hip_bfloat16* w_topth = (__hip_bfloat16*)(ws + OFF_TOPT_H);
  __hip_bfloat16* w_toptl = (__hip_bfloat16*)(ws + OFF_TOPT_L);
  __hip_bfloat16* w_centh = (__hip_bfloat16*)(ws + OFF_CENT_H);
  __hip_bfloat16* w_centl = (__hip_bfloat16*)(ws + OFF_CENT_L);
  __hip_bfloat16* w_bot   = (__hip_bfloat16*)(ws + OFF_BOT);
  float*          w_attn  = ws + OFF_ATTN;
  __hip_bfloat16* w_xth   = (__hip_bfloat16*)(ws + OFF_XT_H);
  __hip_bfloat16* w_xtl   = (__hip_bfloat16*)(ws + OFF_XT_L);
  __hip_bfloat16* w_yt    = (__hip_bfloat16*)(ws + OFF_YT);
  __hip_bfloat16* w_wk1   = (__hip_bfloat16*)(ws + OFF_WK1);
  __hip_bfloat16* w_wk2   = (__hip_bfloat16*)(ws + OFF_WK2);
  __hip_bfloat16* w_wth   = (__hip_bfloat16*)(ws + OFF_WTH);
  __hip_bfloat16* w_wtl   = (__hip_bfloat16*)(ws + OFF_WTL);
  __hip_bfloat16* w_wch   = (__hip_bfloat16*)(ws + OFF_WCH);
  __hip_bfloat16* w_wcl   = (__hip_bfloat16*)(ws + OFF_WCL);
  float* w_pmax  = ws + OFF_PMAX;
  float* w_zpart = ws + OFF_ZPART;
  float* w_MZ    = ws + OFF_MZ;
  (void)in_sizes; (void)n_in; (void)out_size; (void)ws_size;

  // prologue: splits/repacks
  pab_split_x<<<dim3(64, 4, 8), 256, 0, stream>>>(x, w_xth, w_xtl);
  pab_repack_w3<<<dim3(2304), 256, 0, stream>>>(bottom_w, w_wk1);
  pab_repack_w3<<<dim3(2304), 256, 0, stream>>>(out_w, w_wk2);
  pab_split_w1<<<dim3(64), 256, 0, stream>>>(top_w, w_wth, w_wtl);
  pab_split_w1<<<dim3(64), 256, 0, stream>>>(center_w, w_wch, w_wcl);

  // 1x1 convs (split-bf16 MFMA) -> transposed hi/lo [m][p]
  pab_conv1x1_mfma<<<dim3(16, 8), 256, 0, stream>>>(w_xth, w_xtl, w_wth, w_wtl,
                                                    top_b, w_topth, w_toptl);
  pab_conv1x1_mfma<<<dim3(16, 8), 256, 0, stream>>>(w_xth, w_xtl, w_wch, w_wcl,
                                                    center_b, w_centh, w_centl);
  // 3x3 conv -> bot bf16 [c][m]
  pab_conv3x3_mfma<<<dim3(64, 8), 256, 0, stream>>>(w_xth, w_wk1, bottom_b,
                                                    (float*)nullptr, w_bot, 1);
  // global max (approx, 1-term bf16 — exact softmax math for any M)
  pab_pass1max<<<dim3(512), 256, 0, stream>>>(w_centh, w_topth, w_pmax);
  pab_reduceM<<<dim3(8), 64, 0, stream>>>(w_pmax, w_MZ);
  // attention apply (unnormalized) + Z partials
  pab_pass2_mfma<<<dim3(512), 256, 0, stream>>>(w_centh, w_centl, w_topth, w_toptl,
                                                w_bot, w_MZ, w_attn, w_zpart);
  pab_reduceZ<<<dim3(8), 64, 0, stream>>>(w_zpart, w_MZ);
  // fused normalize + residual + transpose -> bf16, then final 3x3 conv
  pab_tcvt2<<<dim3(64, 4, 8), 256, 0, stream>>>(x, w_attn, w_MZ, w_yt);
  pab_conv3x3_mfma<<<dim3(64, 8), 256, 0, stream>>>(w_yt, w_wk2, out_b,
                                                    (float*)d_out, (__hip_bfloat16*)nullptr, 0);
}